// Round 3
// baseline (129.231 us; speedup 1.0000x reference)
//
#include <hip/hip_runtime.h>

typedef _Float16 f16x8 __attribute__((ext_vector_type(8)));
typedef _Float16 f16x4 __attribute__((ext_vector_type(4)));
typedef float    f32x4 __attribute__((ext_vector_type(4)));

// ---------------- workspace layout (bytes) ----------------
#define A16_OFF   0u
#define V16_OFF   16777216u
#define WAP_OFF   33554432u   // packed Wa fragments, 393216 B
#define WVP_OFF   33947648u   // packed Wv fragments, 393216 B
#define CORRT_OFF 34340864u
#define WBT_OFF   34471936u

// =========================================================
// k_pack: Wa/Wv [768,256] fp32 -> MFMA-fragment-packed fp16.
//  Fragment (kc, nb): 64 lanes x 16 B contiguous (1 KB).
//  lane l=(q,lm): holds W[kc*32+q*8+e][nb*16+lm], e=0..7.
//  Grid: 2 z x 24 kc x 1 (4 nb per block) = 192 blocks.
// =========================================================
__global__ __launch_bounds__(256) void k_pack(
    const float* __restrict__ Wa, const float* __restrict__ Wv,
    _Float16* __restrict__ WaP, _Float16* __restrict__ WvP)
{
    int bid = blockIdx.x;
    int z = bid >= 96;
    int r = z ? bid - 96 : bid;
    int kc = r >> 2, nbg = r & 3;
    const float* W = z ? Wv : Wa;
    _Float16* P = z ? WvP : WaP;
    int t = threadIdx.x;
    int l = t & 63, sub = t >> 6;
    int nb = nbg * 4 + sub;
    int q = l >> 4, lm = l & 15;
    int k0 = kc * 32 + q * 8;
    int n = nb * 16 + lm;
    _Float16 tmp[8];
    #pragma unroll
    for (int e = 0; e < 8; ++e)
        tmp[e] = (_Float16)W[(size_t)(k0 + e) * 256 + n];
    *reinterpret_cast<f16x8*>(P + ((size_t)(kc * 16 + nb) * 64 + l) * 8) =
        *reinterpret_cast<const f16x8*>(tmp);
}

// =========================================================
// k_tr: transpose + fp16 convert for corr and Wb (k_fuse inputs).
// =========================================================
__global__ __launch_bounds__(256) void k_tr(
    const float* __restrict__ corr, const float* __restrict__ Wb,
    _Float16* __restrict__ corrT, _Float16* __restrict__ WbT)
{
    __shared__ _Float16 tile[64][72];
    int bid = blockIdx.x;
    const float* src; _Float16* dst; int R, C, tr, tc;
    if (bid < 16) { src = corr; dst = corrT; R = 256; C = 256; tr = bid >> 2; tc = bid & 3; }
    else          { src = Wb;   dst = WbT;   R = 512; C = 64;  tr = bid - 16; tc = 0;       }
    int r0 = tr * 64, c0 = tc * 64;
    int t = threadIdx.x;
    #pragma unroll
    for (int it = 0; it < 16; ++it) {
        int idx = t + it * 256;
        int r = idx >> 6, c = idx & 63;
        tile[r][c] = (_Float16)src[(size_t)(r0 + r) * C + (c0 + c)];
    }
    __syncthreads();
    #pragma unroll
    for (int it = 0; it < 16; ++it) {
        int idx = t + it * 256;
        int c = idx >> 6, r = idx & 63;
        dst[(size_t)(c0 + c) * R + (r0 + r)] = tile[r][c];
    }
}

// =========================================================
// k_proj v3: barrier-free register-streaming GEMM.
//  Wave owns 32 rows x 256 cols. A fp32 -> regs (1-iter prefetch)
//  -> cvt fp16. B from fragment-packed stream (L2). acc f32x4[2][16].
//  Epilogue: per-wave LDS transpose (stride 260) -> f16x8 stores.
//  Grid: 512 blocks x 256 thr; z = bid>>8.
// =========================================================
__global__ __launch_bounds__(256, 2) void k_proj(
    const float* __restrict__ Xa, const float* __restrict__ Xv,
    const _Float16* __restrict__ WaP, const _Float16* __restrict__ WvP,
    const float* __restrict__ ba, const float* __restrict__ bv,
    _Float16* __restrict__ Aout, _Float16* __restrict__ Vout)
{
    __shared__ _Float16 eps[4][16 * 260];   // 33280 B

    const int bid = blockIdx.x;
    const int z = bid >> 8, mb = bid & 255;
    const float*    X    = z ? Xv  : Xa;
    const _Float16* WP   = z ? WvP : WaP;
    const float*    bias = z ? bv  : ba;
    _Float16*       Out  = z ? Vout : Aout;

    const int t = threadIdx.x, lane = t & 63, w = t >> 6;
    const int q = lane >> 4, lm = lane & 15;
    const int r0 = mb * 128 + w * 32;

    const float* A0 = X + (size_t)(r0 + lm) * 768 + q * 8;
    const float* A1 = A0 + 16 * 768;
    const _Float16* Bp = WP + (size_t)lane * 8;

    f32x4 acc[2][16] = {};
    f32x4 p0a, p0b, p1a, p1b;

    p0a = *reinterpret_cast<const f32x4*>(A0);
    p0b = *reinterpret_cast<const f32x4*>(A0 + 4);
    p1a = *reinterpret_cast<const f32x4*>(A1);
    p1b = *reinterpret_cast<const f32x4*>(A1 + 4);

    for (int ks = 0; ks < 24; ++ks) {
        // convert current A to fp16 fragments
        f16x4 c0a = __builtin_convertvector(p0a, f16x4);
        f16x4 c0b = __builtin_convertvector(p0b, f16x4);
        f16x4 c1a = __builtin_convertvector(p1a, f16x4);
        f16x4 c1b = __builtin_convertvector(p1b, f16x4);
        f16x8 af0 = __builtin_shufflevector(c0a, c0b, 0, 1, 2, 3, 4, 5, 6, 7);
        f16x8 af1 = __builtin_shufflevector(c1a, c1b, 0, 1, 2, 3, 4, 5, 6, 7);
        // prefetch next A tile (lands while we do B loads + MFMA)
        if (ks + 1 < 24) {
            const float* a0 = A0 + (ks + 1) * 32;
            const float* a1 = A1 + (ks + 1) * 32;
            p0a = *reinterpret_cast<const f32x4*>(a0);
            p0b = *reinterpret_cast<const f32x4*>(a0 + 4);
            p1a = *reinterpret_cast<const f32x4*>(a1);
            p1b = *reinterpret_cast<const f32x4*>(a1 + 4);
        }
        const _Float16* Bk = Bp + (size_t)ks * 8192;
        #pragma unroll
        for (int nf = 0; nf < 16; ++nf) {
            f16x8 bf = *reinterpret_cast<const f16x8*>(Bk + nf * 512);
            acc[0][nf] = __builtin_amdgcn_mfma_f32_16x16x32_f16(af0, bf, acc[0][nf], 0, 0, 0);
            acc[1][nf] = __builtin_amdgcn_mfma_f32_16x16x32_f16(af1, bf, acc[1][nf], 0, 0, 0);
        }
    }

    // ---- epilogue: acc (+bias) -> per-wave LDS -> coalesced f16x8 stores ----
    float bias16[16];
    #pragma unroll
    for (int nf = 0; nf < 16; ++nf)
        bias16[nf] = bias[nf * 16 + lm];

    _Float16* ep = eps[w];
    #pragma unroll
    for (int half = 0; half < 2; ++half) {
        #pragma unroll
        for (int nf = 0; nf < 16; ++nf)
            #pragma unroll
            for (int r = 0; r < 4; ++r)
                ep[(q * 4 + r) * 260 + nf * 16 + lm] =
                    (_Float16)(acc[half][nf][r] + bias16[nf]);
        __syncthreads();
        #pragma unroll
        for (int i = 0; i < 8; ++i) {
            int idx = i * 64 + lane;
            int row = idx >> 5, c = idx & 31;
            f16x8 vv = *reinterpret_cast<const f16x8*>(ep + row * 260 + c * 8);
            *reinterpret_cast<f16x8*>(Out + (size_t)(r0 + half * 16 + row) * 256 + c * 8) = vv;
        }
        __syncthreads();
    }
}

// =========================================================
// k_fuse: per-batch (512 blocks, 256 thr = 4 waves) — unchanged
// =========================================================
#define SM_A    0u
#define SM_V    33792u
#define SM_AC   67584u
#define SM_CC   101376u
#define SM_ATA  118272u
#define SM_ATV  127488u
#define SM_AWT  136704u
#define SM_VWT  145920u
#define SM_RED  155136u
#define SM_TOTAL 159232u

__global__ __launch_bounds__(256) void k_fuse(
    const _Float16* __restrict__ A16, const _Float16* __restrict__ V16,
    const _Float16* __restrict__ corrT, const _Float16* __restrict__ WbT,
    const float* __restrict__ bb, const float* __restrict__ gamma,
    const float* __restrict__ beta, float* __restrict__ out)
{
    extern __shared__ char sm[];
    _Float16* a_s   = (_Float16*)(sm + SM_A);
    _Float16* v_s   = (_Float16*)(sm + SM_V);
    _Float16* ac_s  = (_Float16*)(sm + SM_AC);
    float*    cc_s  = (float*)(sm + SM_CC);
    _Float16* attAT = (_Float16*)(sm + SM_ATA);
    _Float16* attV  = (_Float16*)(sm + SM_ATV);
    _Float16* awT   = (_Float16*)(sm + SM_AWT);
    _Float16* vwT   = (_Float16*)(sm + SM_VWT);
    float*    red   = (float*)(sm + SM_RED);

    const int b = blockIdx.x;
    const int t = threadIdx.x, lane = t & 63, w = t >> 6;
    const int q = lane >> 4, lm = lane & 15;

    const _Float16* Ab = A16 + (size_t)b * 64 * 256;
    const _Float16* Vb = V16 + (size_t)b * 64 * 256;
    #pragma unroll
    for (int it = 0; it < 8; ++it) {
        int idx = t + it * 256;
        int row = idx >> 5, kc = idx & 31;
        *reinterpret_cast<f16x8*>(a_s + row * 264 + kc * 8) =
            *reinterpret_cast<const f16x8*>(Ab + row * 256 + kc * 8);
        *reinterpret_cast<f16x8*>(v_s + row * 264 + kc * 8) =
            *reinterpret_cast<const f16x8*>(Vb + row * 256 + kc * 8);
    }
    __syncthreads();

    // ac = a @ corr
    {
        f32x4 acc[4][4] = {};
        for (int ks = 0; ks < 8; ++ks) {
            f16x8 af[4];
            #pragma unroll
            for (int mf = 0; mf < 4; ++mf)
                af[mf] = *reinterpret_cast<const f16x8*>(a_s + (mf * 16 + lm) * 264 + ks * 32 + q * 8);
            #pragma unroll
            for (int nf = 0; nf < 4; ++nf) {
                int e = w * 64 + nf * 16 + lm;
                f16x8 bf = *reinterpret_cast<const f16x8*>(corrT + (size_t)e * 256 + ks * 32 + q * 8);
                #pragma unroll
                for (int mf = 0; mf < 4; ++mf)
                    acc[mf][nf] = __builtin_amdgcn_mfma_f32_16x16x32_f16(af[mf], bf, acc[mf][nf], 0, 0, 0);
            }
        }
        #pragma unroll
        for (int mf = 0; mf < 4; ++mf)
            #pragma unroll
            for (int nf = 0; nf < 4; ++nf)
                #pragma unroll
                for (int r = 0; r < 4; ++r)
                    ac_s[(mf * 16 + 4 * q + r) * 264 + (w * 64 + nf * 16 + lm)] = (_Float16)acc[mf][nf][r];
    }
    __syncthreads();

    // cc = ac @ v^T
    {
        f32x4 acc[4] = {};
        for (int ks = 0; ks < 8; ++ks) {
            f16x8 bf = *reinterpret_cast<const f16x8*>(v_s + (w * 16 + lm) * 264 + ks * 32 + q * 8);
            #pragma unroll
            for (int mf = 0; mf < 4; ++mf) {
                f16x8 af = *reinterpret_cast<const f16x8*>(ac_s + (mf * 16 + lm) * 264 + ks * 32 + q * 8);
                acc[mf] = __builtin_amdgcn_mfma_f32_16x16x32_f16(af, bf, acc[mf], 0, 0, 0);
            }
        }
        #pragma unroll
        for (int mf = 0; mf < 4; ++mf)
            #pragma unroll
            for (int r = 0; r < 4; ++r)
                cc_s[(mf * 16 + 4 * q + r) * 66 + (w * 16 + lm)] = acc[mf][r];
    }
    __syncthreads();

    // dual softmax (+identity)
    {
        int j = t & 63, seg = w;
        float cmx = -1e30f, rmx = -1e30f;
        #pragma unroll
        for (int k = 0; k < 16; ++k) {
            int i = seg * 16 + k;
            cmx = fmaxf(cmx, cc_s[i * 66 + j]);
            rmx = fmaxf(rmx, cc_s[j * 66 + i]);
        }
        red[0 * 256 + seg * 64 + j] = cmx;
        red[2 * 256 + seg * 64 + j] = rmx;
        __syncthreads();
        float cm = fmaxf(fmaxf(red[0 * 256 + 0 * 64 + j], red[0 * 256 + 1 * 64 + j]),
                         fmaxf(red[0 * 256 + 2 * 64 + j], red[0 * 256 + 3 * 64 + j]));
        float rm = fmaxf(fmaxf(red[2 * 256 + 0 * 64 + j], red[2 * 256 + 1 * 64 + j]),
                         fmaxf(red[2 * 256 + 2 * 64 + j], red[2 * 256 + 3 * 64 + j]));
        float cs = 0.f, rs = 0.f;
        #pragma unroll
        for (int k = 0; k < 16; ++k) {
            int i = seg * 16 + k;
            cs += __expf(cc_s[i * 66 + j] - cm);
            rs += __expf(cc_s[j * 66 + i] - rm);
        }
        red[1 * 256 + seg * 64 + j] = cs;
        red[3 * 256 + seg * 64 + j] = rs;
        __syncthreads();
        float csum = red[1 * 256 + 0 * 64 + j] + red[1 * 256 + 1 * 64 + j] +
                     red[1 * 256 + 2 * 64 + j] + red[1 * 256 + 3 * 64 + j];
        float rsum = red[3 * 256 + 0 * 64 + j] + red[3 * 256 + 1 * 64 + j] +
                     red[3 * 256 + 2 * 64 + j] + red[3 * 256 + 3 * 64 + j];
        float cinv = 1.f / csum, rinv = 1.f / rsum;
        #pragma unroll
        for (int k = 0; k < 16; ++k) {
            int i = seg * 16 + k;
            float pa = __expf(cc_s[i * 66 + j] - cm) * cinv;
            if (i == j) pa += 1.f;
            attAT[j * 72 + i] = (_Float16)pa;
            float pv = __expf(cc_s[j * 66 + i] - rm) * rinv;
            if (i == j) pv += 1.f;
            attV[j * 72 + i] = (_Float16)pv;
        }
    }

    // aw = a@Wb_top (waves 0,1), vw = v@Wb_bot (waves 2,3)
    {
        int isV = w >> 1, wcol = w & 1;
        const _Float16* src = isV ? v_s : a_s;
        const int doff = isV ? 256 : 0;
        f32x4 acc[4][2] = {};
        for (int ks = 0; ks < 8; ++ks) {
            f16x8 af[4];
            #pragma unroll
            for (int mf = 0; mf < 4; ++mf)
                af[mf] = *reinterpret_cast<const f16x8*>(src + (mf * 16 + lm) * 264 + ks * 32 + q * 8);
            #pragma unroll
            for (int nf = 0; nf < 2; ++nf) {
                int o = wcol * 32 + nf * 16 + lm;
                f16x8 bf = *reinterpret_cast<const f16x8*>(WbT + (size_t)o * 512 + doff + ks * 32 + q * 8);
                #pragma unroll
                for (int mf = 0; mf < 4; ++mf)
                    acc[mf][nf] = __builtin_amdgcn_mfma_f32_16x16x32_f16(af[mf], bf, acc[mf][nf], 0, 0, 0);
            }
        }
        _Float16* dst = isV ? vwT : awT;
        #pragma unroll
        for (int mf = 0; mf < 4; ++mf)
            #pragma unroll
            for (int nf = 0; nf < 2; ++nf)
                #pragma unroll
                for (int r = 0; r < 4; ++r)
                    dst[(wcol * 32 + nf * 16 + lm) * 72 + (mf * 16 + 4 * q + r)] = (_Float16)acc[mf][nf][r];
    }
    __syncthreads();

    // h = attA^T@aw + attV@vw
    f32x4 hacc[4] = {};
    #pragma unroll
    for (int kk = 0; kk < 2; ++kk) {
        f16x8 a1 = *reinterpret_cast<const f16x8*>(attAT + (16 * w + lm) * 72 + kk * 32 + q * 8);
        f16x8 a2 = *reinterpret_cast<const f16x8*>(attV  + (16 * w + lm) * 72 + kk * 32 + q * 8);
        #pragma unroll
        for (int nf = 0; nf < 4; ++nf) {
            f16x8 b1 = *reinterpret_cast<const f16x8*>(awT + (nf * 16 + lm) * 72 + kk * 32 + q * 8);
            f16x8 b2 = *reinterpret_cast<const f16x8*>(vwT + (nf * 16 + lm) * 72 + kk * 32 + q * 8);
            hacc[nf] = __builtin_amdgcn_mfma_f32_16x16x32_f16(a1, b1, hacc[nf], 0, 0, 0);
            hacc[nf] = __builtin_amdgcn_mfma_f32_16x16x32_f16(a2, b2, hacc[nf], 0, 0, 0);
        }
    }

    // +bb, LayerNorm, ReLU, store
    {
        float bbv[4], gv[4], bev[4];
        #pragma unroll
        for (int nf = 0; nf < 4; ++nf) {
            int o = nf * 16 + lm;
            bbv[nf] = bb[o]; gv[nf] = gamma[o]; bev[nf] = beta[o];
        }
        #pragma unroll
        for (int r = 0; r < 4; ++r) {
            float vals[4]; float s1 = 0.f, s2 = 0.f;
            #pragma unroll
            for (int nf = 0; nf < 4; ++nf) {
                float hv = hacc[nf][r] + bbv[nf];
                vals[nf] = hv; s1 += hv; s2 += hv * hv;
            }
            #pragma unroll
            for (int m = 1; m < 16; m <<= 1) {
                s1 += __shfl_xor(s1, m, 64);
                s2 += __shfl_xor(s2, m, 64);
            }
            float mu = s1 * 0.015625f;
            float var = s2 * 0.015625f - mu * mu;
            float rstd = rsqrtf(var + 1e-5f);
            int s = 16 * w + 4 * q + r;
            float* orow = out + ((size_t)b * 64 + s) * 64;
            #pragma unroll
            for (int nf = 0; nf < 4; ++nf) {
                float y = (vals[nf] - mu) * rstd * gv[nf] + bev[nf];
                orow[nf * 16 + lm] = fmaxf(y, 0.f);
            }
        }
    }
}

// =========================================================
extern "C" void kernel_launch(void* const* d_in, const int* in_sizes, int n_in,
                              void* d_out, int out_size, void* d_ws, size_t ws_size,
                              hipStream_t stream) {
    const float* Xa    = (const float*)d_in[0];
    const float* Xv    = (const float*)d_in[1];
    const float* Wa    = (const float*)d_in[2];
    const float* ba    = (const float*)d_in[3];
    const float* Wv    = (const float*)d_in[4];
    const float* bv    = (const float*)d_in[5];
    const float* corr  = (const float*)d_in[6];
    const float* Wb    = (const float*)d_in[7];
    const float* bb    = (const float*)d_in[8];
    const float* gamma = (const float*)d_in[9];
    const float* beta  = (const float*)d_in[10];
    float* out = (float*)d_out;
    char* ws = (char*)d_ws;

    _Float16* a16   = (_Float16*)(ws + A16_OFF);
    _Float16* v16   = (_Float16*)(ws + V16_OFF);
    _Float16* WaP   = (_Float16*)(ws + WAP_OFF);
    _Float16* WvP   = (_Float16*)(ws + WVP_OFF);
    _Float16* corrT = (_Float16*)(ws + CORRT_OFF);
    _Float16* WbT   = (_Float16*)(ws + WBT_OFF);

    hipLaunchKernelGGL(k_pack, dim3(192), dim3(256), 0, stream,
                       Wa, Wv, WaP, WvP);
    hipLaunchKernelGGL(k_tr, dim3(24), dim3(256), 0, stream,
                       corr, Wb, corrT, WbT);
    hipLaunchKernelGGL(k_proj, dim3(512), dim3(256), 0, stream,
                       Xa, Xv, WaP, WvP, ba, bv, a16, v16);
    (void)hipFuncSetAttribute((const void*)k_fuse,
                              hipFuncAttributeMaxDynamicSharedMemorySize, SM_TOTAL);
    hipLaunchKernelGGL(k_fuse, dim3(512), dim3(256), SM_TOTAL, stream,
                       a16, v16, corrT, WbT, bb, gamma, beta, out);
}

// Round 4
// 86.871 us; speedup vs baseline: 1.4876x; 1.4876x over previous
//
#include <hip/hip_runtime.h>

typedef _Float16 f16x8 __attribute__((ext_vector_type(8)));
typedef _Float16 f16x4 __attribute__((ext_vector_type(4)));
typedef float    f32x4 __attribute__((ext_vector_type(4)));

// ---------------- workspace layout (bytes) ----------------
#define A16_OFF   0u
#define V16_OFF   16777216u
#define WAP_OFF   33554432u   // packed Wa chunks: 24*1024*16B = 393216
#define WVP_OFF   33947648u
#define CORRT_OFF 34340864u
#define WBT_OFF   34471936u

__device__ __forceinline__ void gl_lds16(const void* g, void* l) {
    __builtin_amdgcn_global_load_lds(
        (const __attribute__((address_space(1))) void*)g,
        (__attribute__((address_space(3))) void*)l, 16, 0, 0);
}
#define SBAR()   __builtin_amdgcn_s_barrier()
#define SCHED0() __builtin_amdgcn_sched_barrier(0)

// =========================================================
// k_pack: W [768,256] fp32 -> fp16 chunks in staging order.
//  chunk c = ks*1024 + q*256 + col holds W[ks*32+q*8+e][col], e=0..7.
//  One chunk (16 B) per thread; 96 blocks per tensor.
// =========================================================
__global__ __launch_bounds__(256) void k_pack(
    const float* __restrict__ Wa, const float* __restrict__ Wv,
    _Float16* __restrict__ WaP, _Float16* __restrict__ WvP)
{
    int bid = blockIdx.x;
    int z = bid >= 96;
    int b = z ? bid - 96 : bid;
    const float* W = z ? Wv : Wa;
    _Float16* P = z ? WvP : WaP;
    int c = b * 256 + threadIdx.x;
    int col = c & 255, q = (c >> 8) & 3, ks = c >> 10;
    int k0 = ks * 32 + q * 8;
    _Float16 tmp[8];
    #pragma unroll
    for (int e = 0; e < 8; ++e)
        tmp[e] = (_Float16)W[(size_t)(k0 + e) * 256 + col];
    *reinterpret_cast<f16x8*>(P + (size_t)c * 8) = *reinterpret_cast<const f16x8*>(tmp);
}

// =========================================================
// k_tr: transpose + fp16 convert for corr and Wb (k_fuse inputs).
// =========================================================
__global__ __launch_bounds__(256) void k_tr(
    const float* __restrict__ corr, const float* __restrict__ Wb,
    _Float16* __restrict__ corrT, _Float16* __restrict__ WbT)
{
    __shared__ _Float16 tile[64][72];
    int bid = blockIdx.x;
    const float* src; _Float16* dst; int R, C, tr, tc;
    if (bid < 16) { src = corr; dst = corrT; R = 256; C = 256; tr = bid >> 2; tc = bid & 3; }
    else          { src = Wb;   dst = WbT;   R = 512; C = 64;  tr = bid - 16; tc = 0;       }
    int r0 = tr * 64, c0 = tc * 64;
    int t = threadIdx.x;
    #pragma unroll
    for (int it = 0; it < 16; ++it) {
        int idx = t + it * 256;
        int r = idx >> 6, c = idx & 63;
        tile[r][c] = (_Float16)src[(size_t)(r0 + r) * C + (c0 + c)];
    }
    __syncthreads();
    #pragma unroll
    for (int it = 0; it < 16; ++it) {
        int idx = t + it * 256;
        int c = idx >> 6, r = idx & 63;
        dst[(size_t)(c0 + c) * R + (r0 + r)] = tile[r][c];
    }
}

// =========================================================
// k_proj v4: counted-vmcnt double-buffered pipeline (T3/T4).
//  BM=128, BN=256, BK=32. A fp32 + B fp16 both via global_load_lds.
//  Per K-step: ds_read frags -> lgkmcnt(0) -> raw barrier ->
//  STAGE(ks+2) -> 32 MFMA -> vmcnt(8) -> raw barrier.
//  vmcnt(8) leaves the next tile's 8 DMAs in flight (never drain!).
//  LDS 64KB -> 2 blocks/CU. Grid 512 blocks (all resident).
// =========================================================
__global__ __launch_bounds__(256, 2) void k_proj(
    const float* __restrict__ Xa, const float* __restrict__ Xv,
    const _Float16* __restrict__ WaP, const _Float16* __restrict__ WvP,
    const float* __restrict__ ba, const float* __restrict__ bv,
    _Float16* __restrict__ Aout, _Float16* __restrict__ Vout)
{
    __shared__ __align__(16) char Abuf[2][16384];   // 128 rows x 8 chunks x 16B, xor-swizzled content
    __shared__ __align__(16) char Bbuf[2][16384];   // [q][col] chunks, linear

    const int bid = blockIdx.x;
    const int z = bid >> 8, mb = bid & 255;
    const float*    X    = z ? Xv  : Xa;
    const _Float16* WP   = z ? WvP : WaP;
    const float*    bias = z ? bv  : ba;
    _Float16*       Out  = z ? Vout : Aout;
    const int m0 = mb * 128;

    const int t = threadIdx.x, lane = t & 63, w = t >> 6;
    const int wr = w >> 1, wc = w & 1;          // wave tile: rows 64*wr, cols 128*wc
    const int q = lane >> 4, lm = lane & 15;

    f32x4 acc[4][8] = {};

    auto stageA = [&](int ks, int buf) {
        #pragma unroll
        for (int it = 0; it < 4; ++it) {
            int idx = t + it * 256;             // 0..1023: r=idx>>3, c=idx&7
            int r = idx >> 3, c = idx & 7;
            int gc = c ^ (r & 7);               // inverse swizzle on global source
            char* l = Abuf[buf] + (it * 256 + w * 64) * 16;   // wave-uniform base
            gl_lds16(X + (size_t)(m0 + r) * 768 + ks * 32 + gc * 4, l);
        }
    };
    auto stageB = [&](int ks, int buf) {
        #pragma unroll
        for (int it = 0; it < 4; ++it) {
            int idx = t + it * 256;
            char* l = Bbuf[buf] + (it * 256 + w * 64) * 16;
            gl_lds16(WP + ((size_t)ks * 1024 + idx) * 8, l);
        }
    };

    // prologue: two tiles in flight; confirm tile 0 only (vmcnt(8))
    stageA(0, 0); stageB(0, 0);
    stageA(1, 1); stageB(1, 1);
    asm volatile("s_waitcnt vmcnt(8)" ::: "memory"); SCHED0();
    SBAR();

    for (int ks = 0; ks < 24; ++ks) {
        const int cur = ks & 1;
        // ---- read fragments from LDS ----
        f16x8 af[4], bf[8];
        #pragma unroll
        for (int mf = 0; mf < 4; ++mf) {
            int r = wr * 64 + mf * 16 + lm;
            const char* base = Abuf[cur] + r * 128;
            int c0 = (2 * q) ^ (r & 7);
            int c1 = (2 * q + 1) ^ (r & 7);
            f32x4 lo = *reinterpret_cast<const f32x4*>(base + c0 * 16);
            f32x4 hi = *reinterpret_cast<const f32x4*>(base + c1 * 16);
            f16x4 l4 = __builtin_convertvector(lo, f16x4);
            f16x4 h4 = __builtin_convertvector(hi, f16x4);
            af[mf] = __builtin_shufflevector(l4, h4, 0, 1, 2, 3, 4, 5, 6, 7);
        }
        #pragma unroll
        for (int nf = 0; nf < 8; ++nf) {
            int col = wc * 128 + nf * 16 + lm;
            bf[nf] = *reinterpret_cast<const f16x8*>(Bbuf[cur] + (q * 256 + col) * 16);
        }
        asm volatile("s_waitcnt lgkmcnt(0)" ::: "memory"); SCHED0();
        SBAR();                                  // all waves done reading buf[cur]
        // ---- refill the buffer we just freed (lands >=1 round later) ----
        if (ks + 2 < 24) { stageA(ks + 2, cur); stageB(ks + 2, cur); }
        // ---- MFMA ----
        __builtin_amdgcn_s_setprio(1);
        #pragma unroll
        for (int nf = 0; nf < 8; ++nf)
            #pragma unroll
            for (int mf = 0; mf < 4; ++mf)
                acc[mf][nf] = __builtin_amdgcn_mfma_f32_16x16x32_f16(af[mf], bf[nf], acc[mf][nf], 0, 0, 0);
        __builtin_amdgcn_s_setprio(0);
        // ---- counted wait: tile ks+1 ready, tile ks+2 still in flight ----
        if (ks < 22) { asm volatile("s_waitcnt vmcnt(8)" ::: "memory"); }
        else         { asm volatile("s_waitcnt vmcnt(0)" ::: "memory"); }
        SCHED0();
        SBAR();
    }

    // ---- epilogue: acc (+bias) -> LDS fp16 [128][256] -> coalesced stores ----
    float biasv[8];
    #pragma unroll
    for (int nf = 0; nf < 8; ++nf)
        biasv[nf] = bias[wc * 128 + nf * 16 + lm];

    _Float16* Cs = (_Float16*)Abuf;   // 64 KB = 128 x 256 fp16, reuse both buffers
    #pragma unroll
    for (int mf = 0; mf < 4; ++mf)
        #pragma unroll
        for (int nf = 0; nf < 8; ++nf)
            #pragma unroll
            for (int r = 0; r < 4; ++r)
                Cs[(wr * 64 + mf * 16 + q * 4 + r) * 256 + wc * 128 + nf * 16 + lm] =
                    (_Float16)(acc[mf][nf][r] + biasv[nf]);
    __syncthreads();
    #pragma unroll
    for (int it = 0; it < 16; ++it) {
        int idx = t + it * 256;
        int row = idx >> 5, c = idx & 31;
        f16x8 vv = *reinterpret_cast<const f16x8*>(Cs + row * 256 + c * 8);
        *reinterpret_cast<f16x8*>(Out + (size_t)(m0 + row) * 256 + c * 8) = vv;
    }
}

// =========================================================
// k_fuse: per-batch (512 blocks, 256 thr = 4 waves) — unchanged
// =========================================================
#define SM_A    0u
#define SM_V    33792u
#define SM_AC   67584u
#define SM_CC   101376u
#define SM_ATA  118272u
#define SM_ATV  127488u
#define SM_AWT  136704u
#define SM_VWT  145920u
#define SM_RED  155136u
#define SM_TOTAL 159232u

__global__ __launch_bounds__(256) void k_fuse(
    const _Float16* __restrict__ A16, const _Float16* __restrict__ V16,
    const _Float16* __restrict__ corrT, const _Float16* __restrict__ WbT,
    const float* __restrict__ bb, const float* __restrict__ gamma,
    const float* __restrict__ beta, float* __restrict__ out)
{
    extern __shared__ char sm[];
    _Float16* a_s   = (_Float16*)(sm + SM_A);
    _Float16* v_s   = (_Float16*)(sm + SM_V);
    _Float16* ac_s  = (_Float16*)(sm + SM_AC);
    float*    cc_s  = (float*)(sm + SM_CC);
    _Float16* attAT = (_Float16*)(sm + SM_ATA);
    _Float16* attV  = (_Float16*)(sm + SM_ATV);
    _Float16* awT   = (_Float16*)(sm + SM_AWT);
    _Float16* vwT   = (_Float16*)(sm + SM_VWT);
    float*    red   = (float*)(sm + SM_RED);

    const int b = blockIdx.x;
    const int t = threadIdx.x, lane = t & 63, w = t >> 6;
    const int q = lane >> 4, lm = lane & 15;

    const _Float16* Ab = A16 + (size_t)b * 64 * 256;
    const _Float16* Vb = V16 + (size_t)b * 64 * 256;
    #pragma unroll
    for (int it = 0; it < 8; ++it) {
        int idx = t + it * 256;
        int row = idx >> 5, kc = idx & 31;
        *reinterpret_cast<f16x8*>(a_s + row * 264 + kc * 8) =
            *reinterpret_cast<const f16x8*>(Ab + row * 256 + kc * 8);
        *reinterpret_cast<f16x8*>(v_s + row * 264 + kc * 8) =
            *reinterpret_cast<const f16x8*>(Vb + row * 256 + kc * 8);
    }
    __syncthreads();

    // ac = a @ corr
    {
        f32x4 acc[4][4] = {};
        for (int ks = 0; ks < 8; ++ks) {
            f16x8 af[4];
            #pragma unroll
            for (int mf = 0; mf < 4; ++mf)
                af[mf] = *reinterpret_cast<const f16x8*>(a_s + (mf * 16 + lm) * 264 + ks * 32 + q * 8);
            #pragma unroll
            for (int nf = 0; nf < 4; ++nf) {
                int e = w * 64 + nf * 16 + lm;
                f16x8 bf = *reinterpret_cast<const f16x8*>(corrT + (size_t)e * 256 + ks * 32 + q * 8);
                #pragma unroll
                for (int mf = 0; mf < 4; ++mf)
                    acc[mf][nf] = __builtin_amdgcn_mfma_f32_16x16x32_f16(af[mf], bf, acc[mf][nf], 0, 0, 0);
            }
        }
        #pragma unroll
        for (int mf = 0; mf < 4; ++mf)
            #pragma unroll
            for (int nf = 0; nf < 4; ++nf)
                #pragma unroll
                for (int r = 0; r < 4; ++r)
                    ac_s[(mf * 16 + 4 * q + r) * 264 + (w * 64 + nf * 16 + lm)] = (_Float16)acc[mf][nf][r];
    }
    __syncthreads();

    // cc = ac @ v^T
    {
        f32x4 acc[4] = {};
        for (int ks = 0; ks < 8; ++ks) {
            f16x8 bf = *reinterpret_cast<const f16x8*>(v_s + (w * 16 + lm) * 264 + ks * 32 + q * 8);
            #pragma unroll
            for (int mf = 0; mf < 4; ++mf) {
                f16x8 af = *reinterpret_cast<const f16x8*>(ac_s + (mf * 16 + lm) * 264 + ks * 32 + q * 8);
                acc[mf] = __builtin_amdgcn_mfma_f32_16x16x32_f16(af, bf, acc[mf], 0, 0, 0);
            }
        }
        #pragma unroll
        for (int mf = 0; mf < 4; ++mf)
            #pragma unroll
            for (int r = 0; r < 4; ++r)
                cc_s[(mf * 16 + 4 * q + r) * 66 + (w * 16 + lm)] = acc[mf][r];
    }
    __syncthreads();

    // dual softmax (+identity)
    {
        int j = t & 63, seg = w;
        float cmx = -1e30f, rmx = -1e30f;
        #pragma unroll
        for (int k = 0; k < 16; ++k) {
            int i = seg * 16 + k;
            cmx = fmaxf(cmx, cc_s[i * 66 + j]);
            rmx = fmaxf(rmx, cc_s[j * 66 + i]);
        }
        red[0 * 256 + seg * 64 + j] = cmx;
        red[2 * 256 + seg * 64 + j] = rmx;
        __syncthreads();
        float cm = fmaxf(fmaxf(red[0 * 256 + 0 * 64 + j], red[0 * 256 + 1 * 64 + j]),
                         fmaxf(red[0 * 256 + 2 * 64 + j], red[0 * 256 + 3 * 64 + j]));
        float rm = fmaxf(fmaxf(red[2 * 256 + 0 * 64 + j], red[2 * 256 + 1 * 64 + j]),
                         fmaxf(red[2 * 256 + 2 * 64 + j], red[2 * 256 + 3 * 64 + j]));
        float cs = 0.f, rs = 0.f;
        #pragma unroll
        for (int k = 0; k < 16; ++k) {
            int i = seg * 16 + k;
            cs += __expf(cc_s[i * 66 + j] - cm);
            rs += __expf(cc_s[j * 66 + i] - rm);
        }
        red[1 * 256 + seg * 64 + j] = cs;
        red[3 * 256 + seg * 64 + j] = rs;
        __syncthreads();
        float csum = red[1 * 256 + 0 * 64 + j] + red[1 * 256 + 1 * 64 + j] +
                     red[1 * 256 + 2 * 64 + j] + red[1 * 256 + 3 * 64 + j];
        float rsum = red[3 * 256 + 0 * 64 + j] + red[3 * 256 + 1 * 64 + j] +
                     red[3 * 256 + 2 * 64 + j] + red[3 * 256 + 3 * 64 + j];
        float cinv = 1.f / csum, rinv = 1.f / rsum;
        #pragma unroll
        for (int k = 0; k < 16; ++k) {
            int i = seg * 16 + k;
            float pa = __expf(cc_s[i * 66 + j] - cm) * cinv;
            if (i == j) pa += 1.f;
            attAT[j * 72 + i] = (_Float16)pa;
            float pv = __expf(cc_s[j * 66 + i] - rm) * rinv;
            if (i == j) pv += 1.f;
            attV[j * 72 + i] = (_Float16)pv;
        }
    }

    // aw = a@Wb_top (waves 0,1), vw = v@Wb_bot (waves 2,3)
    {
        int isV = w >> 1, wcol = w & 1;
        const _Float16* src = isV ? v_s : a_s;
        const int doff = isV ? 256 : 0;
        f32x4 acc[4][2] = {};
        for (int ks = 0; ks < 8; ++ks) {
            f16x8 af[4];
            #pragma unroll
            for (int mf = 0; mf < 4; ++mf)
                af[mf] = *reinterpret_cast<const f16x8*>(src + (mf * 16 + lm) * 264 + ks * 32 + q * 8);
            #pragma unroll
            for (int nf = 0; nf < 2; ++nf) {
                int o = wcol * 32 + nf * 16 + lm;
                f16x8 bf = *reinterpret_cast<const f16x8*>(WbT + (size_t)o * 512 + doff + ks * 32 + q * 8);
                #pragma unroll
                for (int mf = 0; mf < 4; ++mf)
                    acc[mf][nf] = __builtin_amdgcn_mfma_f32_16x16x32_f16(af[mf], bf, acc[mf][nf], 0, 0, 0);
            }
        }
        _Float16* dst = isV ? vwT : awT;
        #pragma unroll
        for (int mf = 0; mf < 4; ++mf)
            #pragma unroll
            for (int nf = 0; nf < 2; ++nf)
                #pragma unroll
                for (int r = 0; r < 4; ++r)
                    dst[(wcol * 32 + nf * 16 + lm) * 72 + (mf * 16 + 4 * q + r)] = (_Float16)acc[mf][nf][r];
    }
    __syncthreads();

    // h = attA^T@aw + attV@vw
    f32x4 hacc[4] = {};
    #pragma unroll
    for (int kk = 0; kk < 2; ++kk) {
        f16x8 a1 = *reinterpret_cast<const f16x8*>(attAT + (16 * w + lm) * 72 + kk * 32 + q * 8);
        f16x8 a2 = *reinterpret_cast<const f16x8*>(attV  + (16 * w + lm) * 72 + kk * 32 + q * 8);
        #pragma unroll
        for (int nf = 0; nf < 4; ++nf) {
            f16x8 b1 = *reinterpret_cast<const f16x8*>(awT + (nf * 16 + lm) * 72 + kk * 32 + q * 8);
            f16x8 b2 = *reinterpret_cast<const f16x8*>(vwT + (nf * 16 + lm) * 72 + kk * 32 + q * 8);
            hacc[nf] = __builtin_amdgcn_mfma_f32_16x16x32_f16(a1, b1, hacc[nf], 0, 0, 0);
            hacc[nf] = __builtin_amdgcn_mfma_f32_16x16x32_f16(a2, b2, hacc[nf], 0, 0, 0);
        }
    }

    // +bb, LayerNorm, ReLU, store
    {
        float bbv[4], gv[4], bev[4];
        #pragma unroll
        for (int nf = 0; nf < 4; ++nf) {
            int o = nf * 16 + lm;
            bbv[nf] = bb[o]; gv[nf] = gamma[o]; bev[nf] = beta[o];
        }
        #pragma unroll
        for (int r = 0; r < 4; ++r) {
            float vals[4]; float s1 = 0.f, s2 = 0.f;
            #pragma unroll
            for (int nf = 0; nf < 4; ++nf) {
                float hv = hacc[nf][r] + bbv[nf];
                vals[nf] = hv; s1 += hv; s2 += hv * hv;
            }
            #pragma unroll
            for (int m = 1; m < 16; m <<= 1) {
                s1 += __shfl_xor(s1, m, 64);
                s2 += __shfl_xor(s2, m, 64);
            }
            float mu = s1 * 0.015625f;
            float var = s2 * 0.015625f - mu * mu;
            float rstd = rsqrtf(var + 1e-5f);
            int s = 16 * w + 4 * q + r;
            float* orow = out + ((size_t)b * 64 + s) * 64;
            #pragma unroll
            for (int nf = 0; nf < 4; ++nf) {
                float y = (vals[nf] - mu) * rstd * gv[nf] + bev[nf];
                orow[nf * 16 + lm] = fmaxf(y, 0.f);
            }
        }
    }
}

// =========================================================
extern "C" void kernel_launch(void* const* d_in, const int* in_sizes, int n_in,
                              void* d_out, int out_size, void* d_ws, size_t ws_size,
                              hipStream_t stream) {
    const float* Xa    = (const float*)d_in[0];
    const float* Xv    = (const float*)d_in[1];
    const float* Wa    = (const float*)d_in[2];
    const float* ba    = (const float*)d_in[3];
    const float* Wv    = (const float*)d_in[4];
    const float* bv    = (const float*)d_in[5];
    const float* corr  = (const float*)d_in[6];
    const float* Wb    = (const float*)d_in[7];
    const float* bb    = (const float*)d_in[8];
    const float* gamma = (const float*)d_in[9];
    const float* beta  = (const float*)d_in[10];
    float* out = (float*)d_out;
    char* ws = (char*)d_ws;

    _Float16* a16   = (_Float16*)(ws + A16_OFF);
    _Float16* v16   = (_Float16*)(ws + V16_OFF);
    _Float16* WaP   = (_Float16*)(ws + WAP_OFF);
    _Float16* WvP   = (_Float16*)(ws + WVP_OFF);
    _Float16* corrT = (_Float16*)(ws + CORRT_OFF);
    _Float16* WbT   = (_Float16*)(ws + WBT_OFF);

    hipLaunchKernelGGL(k_pack, dim3(192), dim3(256), 0, stream,
                       Wa, Wv, WaP, WvP);
    hipLaunchKernelGGL(k_tr, dim3(24), dim3(256), 0, stream,
                       corr, Wb, corrT, WbT);
    hipLaunchKernelGGL(k_proj, dim3(512), dim3(256), 0, stream,
                       Xa, Xv, WaP, WvP, ba, bv, a16, v16);
    (void)hipFuncSetAttribute((const void*)k_fuse,
                              hipFuncAttributeMaxDynamicSharedMemorySize, SM_TOTAL);
    hipLaunchKernelGGL(k_fuse, dim3(512), dim3(256), SM_TOTAL, stream,
                       a16, v16, corrT, WbT, bb, gamma, beta, out);
}